// Round 7
// baseline (30.460 us; speedup 1.0000x reference)
//
#include <hip/hip_runtime.h>

namespace {

constexpr int H = 256;
constexpr int Wd = 256;
constexpr int TILE = 16;
constexpr float EPS9 = 1e-7f / 9.0f;
constexpr float NINTH = 1.0f / 9.0f;
// s_img row pitch: 20 px * 8 ch + 4 pad -> consecutive rows shift bank sets
// by 4 while keeping 16B alignment for float4 accesses.
constexpr int IPITCH = 164;

// One block = one 16x16 pixel tile of one batch image pair (R4/R6 structure:
// 39 KB LDS, launch_bounds(256,4) -> 16 waves/CU).
// Algebra (validated R3+): Laplacian diagonal cancels (window-mean identity),
// W symmetric -> 13 bands, weight 2 off-center.
// SINGLE DISPATCH (R7): last-block-done reduction replaces the second kernel.
// Re-poison-safe counter: atomicAdd hands out nblocks consecutive values per
// launch, so `old % nblocks == nblocks-1` selects exactly one block per launch
// for ANY starting counter value (incl. the 0xAA poison) — no reset needed.
__global__ __launch_bounds__(256, 4)
void matting_loss_kernel(const float* __restrict__ content,
                         const float* __restrict__ stylized,
                         float* __restrict__ ws,
                         unsigned int* __restrict__ counter,
                         float* __restrict__ out,
                         int nblocks, float inv_denom)
{
    const int b  = blockIdx.z;
    const int x0 = blockIdx.x * TILE;
    const int y0 = blockIdx.y * TILE;
    const int tid = threadIdx.x;
    const int tx = tid & (TILE - 1);
    const int ty = tid >> 4;

    __shared__ __align__(16) float s_img[20 * IPITCH];     // [y][x*8 + m*4 + c]
    __shared__ __align__(16) float s_muk[2][18][18][4];    // mu0..2, scale
    __shared__ __align__(16) float s_A[2][18][18][6];      // a00,a01,a02,a11,a12,a22
    __shared__ float s_red[4];
    __shared__ int s_last;

    const size_t bofs = (size_t)b * 3 * H * Wd;
    const float* img0 = content + bofs;
    const float* img1 = stylized + bofs;

    // ---- Phase 1: stage 20x20 image tile (+2 halo), clamped ----
    for (int p = tid; p < 400; p += 256) {
        const int py = p / 20, px = p - py * 20;
        const int gy = min(max(y0 - 2 + py, 0), H - 1);
        const int gx = min(max(x0 - 2 + px, 0), Wd - 1);
        const int gi = gy * Wd + gx;
        float4 v0, v1;
        v0.x = img0[gi]; v0.y = img0[H * Wd + gi]; v0.z = img0[2 * H * Wd + gi]; v0.w = 0.f;
        v1.x = img1[gi]; v1.y = img1[H * Wd + gi]; v1.z = img1[2 * H * Wd + gi]; v1.w = 0.f;
        float* dst = &s_img[py * IPITCH + px * 8];
        *reinterpret_cast<float4*>(dst)     = v0;
        *reinterpret_cast<float4*>(dst + 4) = v1;
    }
    __syncthreads();

    // ---- Phase 2: per-center stats (mean + inverse covariance) ----
    for (int p = tid; p < 324; p += 256) {
        const int cy = p / 18, cx = p - cy * 18;
        const int gy = y0 - 1 + cy, gx = x0 - 1 + cx;
        const bool valid = (gy >= 1) && (gy <= H - 2) && (gx >= 1) && (gx <= Wd - 2);
        const float scale = valid ? NINTH : 0.0f;
        #pragma unroll
        for (int m = 0; m < 2; ++m) {
            float s0=0.f,s1=0.f,s2=0.f,q00=0.f,q01=0.f,q02=0.f,q11=0.f,q12=0.f,q22=0.f;
            #pragma unroll
            for (int wy = 0; wy < 3; ++wy)
                #pragma unroll
                for (int wx = 0; wx < 3; ++wx) {
                    const float4 v = *reinterpret_cast<const float4*>(
                        &s_img[(cy + wy) * IPITCH + (cx + wx) * 8 + m * 4]);
                    s0 += v.x; s1 += v.y; s2 += v.z;
                    q00 += v.x * v.x; q01 += v.x * v.y; q02 += v.x * v.z;
                    q11 += v.y * v.y; q12 += v.y * v.z; q22 += v.z * v.z;
                }
            const float mu0 = s0 * NINTH, mu1 = s1 * NINTH, mu2 = s2 * NINTH;
            const float c00 = q00 * NINTH - mu0 * mu0 + EPS9;
            const float c01 = q01 * NINTH - mu0 * mu1;
            const float c02 = q02 * NINTH - mu0 * mu2;
            const float c11 = q11 * NINTH - mu1 * mu1 + EPS9;
            const float c12 = q12 * NINTH - mu1 * mu2;
            const float c22 = q22 * NINTH - mu2 * mu2 + EPS9;
            const float m00 = c11 * c22 - c12 * c12;
            const float m01 = c02 * c12 - c01 * c22;
            const float m02 = c01 * c12 - c02 * c11;
            const float det = c00 * m00 + c01 * m01 + c02 * m02;
            // invalid centers never divide; A=0 + scale=0 kills contribution.
            const float invdet = valid ? (1.0f / det) : 0.0f;
            float4 muk; muk.x = mu0; muk.y = mu1; muk.z = mu2; muk.w = scale;
            *reinterpret_cast<float4*>(&s_muk[m][cy][cx][0]) = muk;
            float* A = &s_A[m][cy][cx][0];
            float2 a0; a0.x = m00 * invdet;                  a0.y = m01 * invdet;
            float2 a1; a1.x = m02 * invdet;                  a1.y = (c00*c22 - c02*c02) * invdet;
            float2 a2; a2.x = (c01*c02 - c00*c12) * invdet;  a2.y = (c00*c11 - c01*c01) * invdet;
            reinterpret_cast<float2*>(A)[0] = a0;
            reinterpret_cast<float2*>(A)[1] = a1;
            reinterpret_cast<float2*>(A)[2] = a2;
        }
    }
    __syncthreads();

    // ---- Phase 3: sequential-image band accumulation (R6, validated) ----
    float dd[13];
    #pragma unroll
    for (int q = 0; q < 13; ++q) dd[q] = 0.f;

    #pragma unroll
    for (int m = 0; m < 2; ++m) {
        const float sign = (m == 0) ? -1.0f : 1.0f;
        const float4 Ii = *reinterpret_cast<const float4*>(
            &s_img[(ty + 2) * IPITCH + (tx + 2) * 8 + m * 4]);

        float st[3][3][3];   // [ey][ex][ch]
        float ck[3][3];
        #pragma unroll
        for (int ey = 0; ey < 3; ++ey)
        #pragma unroll
        for (int ex = 0; ex < 3; ++ex) {
            const float4 muk = *reinterpret_cast<const float4*>(&s_muk[m][ty + ey][tx + ex][0]);
            const float* Ap = &s_A[m][ty + ey][tx + ex][0];
            const float2 a0 = reinterpret_cast<const float2*>(Ap)[0];  // a00,a01
            const float2 a1 = reinterpret_cast<const float2*>(Ap)[1];  // a02,a11
            const float2 a2 = reinterpret_cast<const float2*>(Ap)[2];  // a12,a22
            const float u0 = Ii.x - muk.x, u1 = Ii.y - muk.y, u2 = Ii.z - muk.z;
            const float t0 = a0.x*u0 + a0.y*u1 + a1.x*u2;
            const float t1 = a0.y*u0 + a1.y*u1 + a2.x*u2;
            const float t2 = a1.x*u0 + a2.x*u1 + a2.y*u2;
            const float s = muk.w;
            st[ey][ex][0] = s*t0; st[ey][ex][1] = s*t1; st[ey][ex][2] = s*t2;
            ck[ey][ex] = s * (1.0f - (t0*muk.x + t1*muk.y + t2*muk.z));
        }

        #pragma unroll
        for (int by = 2; by <= 4; ++by) {
            float4 Jr[5];
            const float* jrow = &s_img[(ty + by) * IPITCH + tx * 8 + m * 4];
            #pragma unroll
            for (int q = 0; q < 5; ++q) {
                if (by == 2 && q < 2) continue;
                Jr[q] = *reinterpret_cast<const float4*>(jrow + q * 8);
            }
            float Rk[3], R[3][3];
            #pragma unroll
            for (int ex = 0; ex < 3; ++ex) {
                float rk = 0.f, r0 = 0.f, r1 = 0.f, r2 = 0.f;
                #pragma unroll
                for (int ey = 0; ey < 3; ++ey) {
                    if (ey >= by - 2) {   // compile-time after unroll
                        rk += ck[ey][ex];
                        r0 += st[ey][ex][0]; r1 += st[ey][ex][1]; r2 += st[ey][ex][2];
                    }
                }
                Rk[ex] = rk; R[ex][0] = r0; R[ex][1] = r1; R[ex][2] = r2;
            }
            #pragma unroll
            for (int bx = 0; bx < 5; ++bx) {
                if (by == 2 && bx < 2) continue;   // only bands >= center
                float Tk = 0.f, T0 = 0.f, T1 = 0.f, T2 = 0.f;
                #pragma unroll
                for (int ex = 0; ex < 3; ++ex) {
                    if (ex >= bx - 2 && ex <= bx) {
                        Tk += Rk[ex];
                        T0 += R[ex][0]; T1 += R[ex][1]; T2 += R[ex][2];
                    }
                }
                const int idx = (by - 2) * 5 + bx - 2;   // compile-time const
                const float4 J = Jr[bx];
                dd[idx] += sign * (Tk + T0 * J.x + T1 * J.y + T2 * J.z);
            }
        }
    }

    float loss = dd[0] * dd[0];            // center band, weight 1
    float loss2 = 0.f;
    #pragma unroll
    for (int q = 1; q < 13; ++q) loss2 += dd[q] * dd[q];
    loss += 2.0f * loss2;                  // symmetry weight

    // ---- Phase 4: block reduce -> partial store -> last-block final reduce ----
    #pragma unroll
    for (int off = 32; off >= 1; off >>= 1)
        loss += __shfl_down(loss, off, 64);
    if ((tid & 63) == 0) s_red[tid >> 6] = loss;
    __syncthreads();

    const int bid = (blockIdx.z * gridDim.y + blockIdx.y) * gridDim.x + blockIdx.x;
    if (tid == 0) {
        ws[bid] = s_red[0] + s_red[1] + s_red[2] + s_red[3];
        __threadfence();   // release: make partial visible device-wide
        const unsigned int old = atomicAdd(counter, 1u);
        s_last = ((old % (unsigned)nblocks) == (unsigned)(nblocks - 1)) ? 1 : 0;
    }
    __syncthreads();

    if (s_last) {
        __threadfence();   // acquire: see all blocks' partials
        float acc = 0.f;
        for (int i = tid; i < nblocks; i += 256) acc += ws[i];
        #pragma unroll
        for (int off = 32; off >= 1; off >>= 1)
            acc += __shfl_down(acc, off, 64);
        if ((tid & 63) == 0) s_red[tid >> 6] = acc;
        __syncthreads();
        if (tid == 0)
            out[0] = (s_red[0] + s_red[1] + s_red[2] + s_red[3]) * inv_denom;
    }
}

} // namespace

extern "C" void kernel_launch(void* const* d_in, const int* in_sizes, int n_in,
                              void* d_out, int out_size, void* d_ws, size_t ws_size,
                              hipStream_t stream) {
    const float* content  = (const float*)d_in[0];
    const float* stylized = (const float*)d_in[1];
    float* out = (float*)d_out;
    float* ws  = (float*)d_ws;
    // counter lives past the partials (separate cacheline region)
    unsigned int* counter = (unsigned int*)((char*)d_ws + 8192);

    const int B = in_sizes[0] / (3 * H * Wd);
    const float inv_denom =
        1.0f / ((float)B * (float)(H * Wd) * (float)(H * Wd));

    dim3 grid(Wd / TILE, H / TILE, B);
    const int nblocks = grid.x * grid.y * grid.z;
    matting_loss_kernel<<<grid, 256, 0, stream>>>(content, stylized, ws,
                                                  counter, out, nblocks, inv_denom);
}

// Round 8
// 20.897 us; speedup vs baseline: 1.4576x; 1.4576x over previous
//
#include <hip/hip_runtime.h>

namespace {

constexpr int H = 256;
constexpr int Wd = 256;
constexpr int TW = 16;   // tile width
constexpr int TH = 32;   // tile height
constexpr float EPS9 = 1e-7f / 9.0f;
constexpr float NINTH = 1.0f / 9.0f;
// per-image s_img plane: 4 floats/px (rgb+pad), row = 20 px + 1 px pad
constexpr int IP = 21 * 4;   // 84 floats per row

// One block = one 16x32 tile; thread owns VERTICAL pixel pair (tx, 2ty/2ty+1).
// Pairing shares center-stat records (18->12 reads) and J rows (26->18) per
// pair at unchanged 16 B lane stride (conflict-free; R5's horizontal pairing
// had a 128 B stride -> same-bank serialization, which confounded it).
// Images processed SEQUENTIALLY through phase2+phase3 so only one image's
// stats live in LDS (48.7 KB -> fits 512-block grid at 2 blocks/CU).
// Algebra (validated R3+): diagonal cancels, W symmetric -> 13 bands,
// weight 2 off-center. Finish: partials to ws, kernel 2 reduces (R4/R6;
// single-address atomics cost ~10 us — R7 post-mortem).
__global__ __launch_bounds__(256, 2)
void matting_loss_kernel(const float* __restrict__ content,
                         const float* __restrict__ stylized,
                         float* __restrict__ ws)
{
    const int b  = blockIdx.z;
    const int x0 = blockIdx.x * TW;
    const int y0 = blockIdx.y * TH;
    const int tid = threadIdx.x;
    const int tx  = tid & 15;    // column 0..15
    const int typ = tid >> 4;    // pair-row 0..15 -> pixel rows 2typ, 2typ+1

    __shared__ __align__(16) float s_img0[36 * IP];    // image 0, [row][px*4+c]
    __shared__ __align__(16) float s_img1[36 * IP];    // image 1
    __shared__ __align__(16) float s_muk[34][18][4];   // current image: mu0..2, scale
    __shared__ __align__(16) float s_A[34][18][6];     // a00,a01,a02,a11,a12,a22
    __shared__ float s_red[4];

    const size_t bofs = (size_t)b * 3 * H * Wd;
    const float* img0 = content + bofs;
    const float* img1 = stylized + bofs;

    // ---- Phase 1: stage 20x36 tile (+2 halo), clamped ----
    for (int p = tid; p < 720; p += 256) {
        const int py = p / 20, px = p - py * 20;
        const int gy = min(max(y0 - 2 + py, 0), H - 1);
        const int gx = min(max(x0 - 2 + px, 0), Wd - 1);
        const int gi = gy * Wd + gx;
        float4 v0, v1;
        v0.x = img0[gi]; v0.y = img0[H * Wd + gi]; v0.z = img0[2 * H * Wd + gi]; v0.w = 0.f;
        v1.x = img1[gi]; v1.y = img1[H * Wd + gi]; v1.z = img1[2 * H * Wd + gi]; v1.w = 0.f;
        *reinterpret_cast<float4*>(&s_img0[py * IP + px * 4]) = v0;
        *reinterpret_cast<float4*>(&s_img1[py * IP + px * 4]) = v1;
    }

    float ddA[13], ddB[13];
    #pragma unroll
    for (int q = 0; q < 13; ++q) { ddA[q] = 0.f; ddB[q] = 0.f; }

    #pragma unroll
    for (int m = 0; m < 2; ++m) {
        const float* simg = (m == 0) ? s_img0 : s_img1;
        const float sign  = (m == 0) ? -1.0f : 1.0f;

        __syncthreads();   // phase1 done (m=0) / prior phase3 reads done (m=1)

        // ---- Phase 2: stats for image m, 34x18 = 612 centers ----
        for (int p = tid; p < 612; p += 256) {
            const int cy = p / 18, cx = p - cy * 18;
            const int gy = y0 + cy - 1, gx = x0 + cx - 1;
            const bool valid = (gy >= 1) && (gy <= H - 2) && (gx >= 1) && (gx <= Wd - 2);
            const float scale = valid ? NINTH : 0.0f;
            float s0=0.f,s1=0.f,s2=0.f,q00=0.f,q01=0.f,q02=0.f,q11=0.f,q12=0.f,q22=0.f;
            #pragma unroll
            for (int wy = 0; wy < 3; ++wy)
                #pragma unroll
                for (int wx = 0; wx < 3; ++wx) {
                    const float4 v = *reinterpret_cast<const float4*>(
                        &simg[(cy + wy) * IP + (cx + wx) * 4]);
                    s0 += v.x; s1 += v.y; s2 += v.z;
                    q00 += v.x * v.x; q01 += v.x * v.y; q02 += v.x * v.z;
                    q11 += v.y * v.y; q12 += v.y * v.z; q22 += v.z * v.z;
                }
            const float mu0 = s0 * NINTH, mu1 = s1 * NINTH, mu2 = s2 * NINTH;
            const float c00 = q00 * NINTH - mu0 * mu0 + EPS9;
            const float c01 = q01 * NINTH - mu0 * mu1;
            const float c02 = q02 * NINTH - mu0 * mu2;
            const float c11 = q11 * NINTH - mu1 * mu1 + EPS9;
            const float c12 = q12 * NINTH - mu1 * mu2;
            const float c22 = q22 * NINTH - mu2 * mu2 + EPS9;
            const float m00 = c11 * c22 - c12 * c12;
            const float m01 = c02 * c12 - c01 * c22;
            const float m02 = c01 * c12 - c02 * c11;
            const float det = c00 * m00 + c01 * m01 + c02 * m02;
            // invalid centers never divide; A=0 + scale=0 kills contribution.
            const float invdet = valid ? (1.0f / det) : 0.0f;
            float4 muk; muk.x = mu0; muk.y = mu1; muk.z = mu2; muk.w = scale;
            *reinterpret_cast<float4*>(&s_muk[cy][cx][0]) = muk;
            float* A = &s_A[cy][cx][0];
            float2 a0; a0.x = m00 * invdet;                  a0.y = m01 * invdet;
            float2 a1; a1.x = m02 * invdet;                  a1.y = (c00*c22 - c02*c02) * invdet;
            float2 a2; a2.x = (c01*c02 - c00*c12) * invdet;  a2.y = (c00*c11 - c01*c01) * invdet;
            reinterpret_cast<float2*>(A)[0] = a0;
            reinterpret_cast<float2*>(A)[1] = a1;
            reinterpret_cast<float2*>(A)[2] = a2;
        }
        __syncthreads();

        // ---- Phase 3: pair t-records (12 record reads serve both pixels) ----
        const int r0 = 2 * typ;   // pixel A tile-row; B = r0+1
        float stA[3][3][3], ckA[3][3];
        float stB[3][3][3], ckB[3][3];

        const float4 IiA = *reinterpret_cast<const float4*>(&simg[(r0 + 2) * IP + (tx + 2) * 4]);
        const float4 IiB = *reinterpret_cast<const float4*>(&simg[(r0 + 3) * IP + (tx + 2) * 4]);

        #pragma unroll
        for (int ey0 = 0; ey0 < 4; ++ey0)
        #pragma unroll
        for (int ex = 0; ex < 3; ++ex) {
            const float4 muk = *reinterpret_cast<const float4*>(&s_muk[r0 + ey0][tx + ex][0]);
            const float* Ap = &s_A[r0 + ey0][tx + ex][0];
            const float2 a0 = reinterpret_cast<const float2*>(Ap)[0];  // a00,a01
            const float2 a1 = reinterpret_cast<const float2*>(Ap)[1];  // a02,a11
            const float2 a2 = reinterpret_cast<const float2*>(Ap)[2];  // a12,a22
            const float s = muk.w;
            if (ey0 < 3) {   // record row serves pixel A (rel row ey0)
                const float u0 = IiA.x - muk.x, u1 = IiA.y - muk.y, u2 = IiA.z - muk.z;
                const float t0 = a0.x*u0 + a0.y*u1 + a1.x*u2;
                const float t1 = a0.y*u0 + a1.y*u1 + a2.x*u2;
                const float t2 = a1.x*u0 + a2.x*u1 + a2.y*u2;
                stA[ey0][ex][0] = s*t0; stA[ey0][ex][1] = s*t1; stA[ey0][ex][2] = s*t2;
                ckA[ey0][ex] = s * (1.0f - (t0*muk.x + t1*muk.y + t2*muk.z));
            }
            if (ey0 > 0) {   // serves pixel B (rel row ey0-1)
                const float u0 = IiB.x - muk.x, u1 = IiB.y - muk.y, u2 = IiB.z - muk.z;
                const float t0 = a0.x*u0 + a0.y*u1 + a1.x*u2;
                const float t1 = a0.y*u0 + a1.y*u1 + a2.x*u2;
                const float t2 = a1.x*u0 + a2.x*u1 + a2.y*u2;
                stB[ey0-1][ex][0] = s*t0; stB[ey0-1][ex][1] = s*t1; stB[ey0-1][ex][2] = s*t2;
                ckB[ey0-1][ex] = s * (1.0f - (t0*muk.x + t1*muk.y + t2*muk.z));
            }
        }

        // ---- Band accumulation over 4 shared J rows ----
        // J row jr (abs tile-img row r0+2+jr) serves pixel A band-row by=2+jr
        // (jr<=2) and pixel B band-row by=1+jr (jr>=1).
        #define BAND_ROW(ST, CK, DD, BY)                                          \
        {                                                                         \
            float Rk[3], R[3][3];                                                 \
            _Pragma("unroll")                                                     \
            for (int ex = 0; ex < 3; ++ex) {                                      \
                float rk = 0.f, rr0 = 0.f, rr1 = 0.f, rr2 = 0.f;                  \
                _Pragma("unroll")                                                 \
                for (int ey = 0; ey < 3; ++ey) {                                  \
                    if (ey >= (BY) - 2) {                                         \
                        rk  += CK[ey][ex];                                        \
                        rr0 += ST[ey][ex][0]; rr1 += ST[ey][ex][1];               \
                        rr2 += ST[ey][ex][2];                                     \
                    }                                                             \
                }                                                                 \
                Rk[ex] = rk; R[ex][0] = rr0; R[ex][1] = rr1; R[ex][2] = rr2;      \
            }                                                                     \
            _Pragma("unroll")                                                     \
            for (int bx = 0; bx < 5; ++bx) {                                      \
                if ((BY) == 2 && bx < 2) continue;                                \
                float Tk = 0.f, T0 = 0.f, T1 = 0.f, T2 = 0.f;                     \
                _Pragma("unroll")                                                 \
                for (int ex = 0; ex < 3; ++ex) {                                  \
                    if (ex >= bx - 2 && ex <= bx) {                               \
                        Tk += Rk[ex];                                             \
                        T0 += R[ex][0]; T1 += R[ex][1]; T2 += R[ex][2];           \
                    }                                                             \
                }                                                                 \
                const int idx = ((BY) - 2) * 5 + bx - 2;                          \
                const float4 J = Jr[bx];                                          \
                DD[idx] += sign * (Tk + T0 * J.x + T1 * J.y + T2 * J.z);          \
            }                                                                     \
        }

        #pragma unroll
        for (int jr = 0; jr < 4; ++jr) {
            float4 Jr[5];
            const float* jrow = &simg[(r0 + 2 + jr) * IP + tx * 4];
            #pragma unroll
            for (int q = 0; q < 5; ++q) {
                if (jr == 0 && q < 2) continue;   // only by=2, bx>=2 needed
                Jr[q] = *reinterpret_cast<const float4*>(jrow + q * 4);
            }
            if (jr <= 2) BAND_ROW(stA, ckA, ddA, (2 + jr))
            if (jr >= 1) BAND_ROW(stB, ckB, ddB, (1 + jr))
        }
        #undef BAND_ROW
    }

    // ---- Loss: weight 1 center band (idx 0), weight 2 others (symmetry) ----
    float loss1 = ddA[0] * ddA[0] + ddB[0] * ddB[0];
    float loss2 = 0.f;
    #pragma unroll
    for (int q = 1; q < 13; ++q) loss2 += ddA[q] * ddA[q] + ddB[q] * ddB[q];
    float loss = loss1 + 2.0f * loss2;

    // ---- Phase 4: block reduce, one plain store per block ----
    #pragma unroll
    for (int off = 32; off >= 1; off >>= 1)
        loss += __shfl_down(loss, off, 64);
    if ((tid & 63) == 0) s_red[tid >> 6] = loss;
    __syncthreads();
    if (tid == 0) {
        const int bid = (blockIdx.z * gridDim.y + blockIdx.y) * gridDim.x + blockIdx.x;
        ws[bid] = s_red[0] + s_red[1] + s_red[2] + s_red[3];
    }
}

// Kernel 2: deterministic reduction of per-block partials.
__global__ __launch_bounds__(256)
void reduce_kernel(const float* __restrict__ ws, float* __restrict__ out,
                   int n, float inv_denom)
{
    __shared__ float s_red[4];
    const int tid = threadIdx.x;
    float acc = 0.f;
    for (int i = tid; i < n; i += 256) acc += ws[i];
    #pragma unroll
    for (int off = 32; off >= 1; off >>= 1)
        acc += __shfl_down(acc, off, 64);
    if ((tid & 63) == 0) s_red[tid >> 6] = acc;
    __syncthreads();
    if (tid == 0)
        out[0] = (s_red[0] + s_red[1] + s_red[2] + s_red[3]) * inv_denom;
}

} // namespace

extern "C" void kernel_launch(void* const* d_in, const int* in_sizes, int n_in,
                              void* d_out, int out_size, void* d_ws, size_t ws_size,
                              hipStream_t stream) {
    const float* content  = (const float*)d_in[0];
    const float* stylized = (const float*)d_in[1];
    float* out = (float*)d_out;
    float* ws  = (float*)d_ws;

    const int B = in_sizes[0] / (3 * H * Wd);
    const float inv_denom =
        1.0f / ((float)B * (float)(H * Wd) * (float)(H * Wd));

    dim3 grid(Wd / TW, H / TH, B);
    const int nblocks = grid.x * grid.y * grid.z;
    matting_loss_kernel<<<grid, 256, 0, stream>>>(content, stylized, ws);
    reduce_kernel<<<1, 256, 0, stream>>>(ws, out, nblocks, inv_denom);
}